// Round 15
// baseline (389.621 us; speedup 1.0000x reference)
//
#include <hip/hip_runtime.h>

typedef unsigned short u16;
typedef unsigned int u32;
typedef __bf16 bf16x8 __attribute__((ext_vector_type(8)));
typedef u16 u16x8 __attribute__((ext_vector_type(8)));
typedef float f32x4 __attribute__((ext_vector_type(4)));

#define MFMA(a, b, c) __builtin_amdgcn_mfma_f32_16x16x32_bf16(a, b, c, 0, 0, 0)

__device__ __forceinline__ u16 f2bf(float x) {
    u32 u = __builtin_bit_cast(u32, x);
    u32 r = (u + 0x7FFFu + ((u >> 16) & 1u)) >> 16;
    return (u16)r;
}
__device__ __forceinline__ float bf2f(u16 h) {
    u32 u = ((u32)h) << 16;
    return __builtin_bit_cast(float, u);
}
__device__ __forceinline__ u32 addpk(u32 a, u32 b) {
    float lo = bf2f((u16)(a & 0xffffu)) + bf2f((u16)(b & 0xffffu));
    float hi = bf2f((u16)(a >> 16)) + bf2f((u16)(b >> 16));
    return (u32)f2bf(lo) | ((u32)f2bf(hi) << 16);
}
__device__ __forceinline__ uint4 addpk4(uint4 a, uint4 b) {
    uint4 o;
    o.x = addpk(a.x, b.x); o.y = addpk(a.y, b.y);
    o.z = addpk(a.z, b.z); o.w = addpk(a.w, b.w);
    return o;
}
__device__ __forceinline__ float silu_f(float x) {
    return x * __builtin_amdgcn_rcpf(1.f + __expf(-x));
}
__device__ __forceinline__ bf16x8 ldfrag(const u16* p) {
    return __builtin_bit_cast(bf16x8, *(const u16x8*)p);
}

// ---------------- h -> bf16 table (+ compact coords table) ----------------
__global__ void k_prep(const float* __restrict__ nf, u16* __restrict__ hbf,
                       float4* __restrict__ cpk, int NN) {
    int idx = blockIdx.x * 256 + threadIdx.x;
    int i = idx >> 4, p = idx & 15;
    if (i >= NN) return;
    const float* src = nf + (size_t)i * 131 + 3 + p * 8;
    u16x8 v;
#pragma unroll
    for (int j = 0; j < 8; ++j) v[j] = f2bf(src[j]);
    *(u16x8*)(hbf + (size_t)i * 128 + p * 8) = v;
    if (cpk && p == 0) {
        const float* c = nf + (size_t)i * 131;
        cpk[i] = make_float4(c[0], c[1], c[2], 0.f);
    }
}

// ---------------- degree histogram ----------------
__global__ void k_hist(const int* __restrict__ first, int* __restrict__ cnt, int NE) {
    int e = blockIdx.x * 256 + threadIdx.x;
    if (e < NE) atomicAdd(&cnt[first[e]], 1);
}

// ---------------- counting-sort: scan + scatter ----------------
__global__ void k_scanA(const int* __restrict__ cnt, int* __restrict__ cursor,
                        int* __restrict__ bsum, int NN) {
    __shared__ int wsum[4];
    const int t = threadIdx.x;
    const int base = blockIdx.x * 1024 + t * 4;
    int v0 = base + 0 < NN ? cnt[base + 0] : 0;
    int v1 = base + 1 < NN ? cnt[base + 1] : 0;
    int v2 = base + 2 < NN ? cnt[base + 2] : 0;
    int v3 = base + 3 < NN ? cnt[base + 3] : 0;
    const int s = v0 + v1 + v2 + v3;
    const int lane = t & 63, w = t >> 6;
    int x = s;
#pragma unroll
    for (int d = 1; d < 64; d <<= 1) {
        int y = __shfl_up(x, d);
        if (lane >= d) x += y;
    }
    if (lane == 63) wsum[w] = x;
    __syncthreads();
    int wbase = 0;
    for (int k = 0; k < w; ++k) wbase += wsum[k];
    int run = wbase + x - s;
    if (base + 0 < NN) cursor[base + 0] = run; run += v0;
    if (base + 1 < NN) cursor[base + 1] = run; run += v1;
    if (base + 2 < NN) cursor[base + 2] = run; run += v2;
    if (base + 3 < NN) cursor[base + 3] = run;
    if (t == 255) bsum[blockIdx.x] = wbase + x;
}

__global__ void k_scanB(int* bsum, int NB) {
    if (threadIdx.x == 0 && blockIdx.x == 0) {
        int run = 0;
        for (int b = 0; b < NB; ++b) { int t = bsum[b]; bsum[b] = run; run += t; }
    }
}

__global__ void k_scanC(int* __restrict__ cursor, const int* __restrict__ bsum, int NN) {
    int i = blockIdx.x * 256 + threadIdx.x;
    if (i < NN) cursor[i] += bsum[i >> 10];
}

__global__ void k_scatter(const int* __restrict__ first, const int* __restrict__ second,
                          int* __restrict__ cursor, int4* __restrict__ sorted, int NE) {
    int e = blockIdx.x * 256 + threadIdx.x;
    if (e < NE) {
        int f = first[e];
        int pos = atomicAdd(&cursor[f], 1);
        sorted[pos] = make_int4(f, second[e], e, 0);
    }
}

// ---------------- Y precompute (4 waves x 32 cols, high occupancy) ----------------
// Yf = h@We1[0:128]+be1, Ys = h@We1[128:256]. Weights 64 VGPR/wave.
__global__ __launch_bounds__(256, 2) void k_ymm(
    const u16* __restrict__ hbf, const float* __restrict__ We1, const float* __restrict__ be1,
    u16* __restrict__ Yf, u16* __restrict__ Ys, int NN, int ntiles) {
    __shared__ u16 Hs[32 * 136];
    const int tid = threadIdx.x;
    const int lane = tid & 63;
    const int wv = tid >> 6;          // 0..3, owns cols [wv*32, wv*32+32)
    const int lhi = lane >> 4, llo = lane & 15;
    const f32x4 fzero = {0.f, 0.f, 0.f, 0.f};

    bf16x8 wf[2][4], wsx[2][4];
    float b1r[2];
#pragma unroll
    for (int ni = 0; ni < 2; ++ni) {
        const int c = wv * 32 + ni * 16 + llo;
        b1r[ni] = be1[c];
#pragma unroll
        for (int t = 0; t < 4; ++t) {
            u16x8 ta, tb;
#pragma unroll
            for (int j = 0; j < 8; ++j) {
                int k = t * 32 + lhi * 8 + j;
                ta[j] = f2bf(We1[(size_t)k * 128 + c]);
                tb[j] = f2bf(We1[(size_t)(128 + k) * 128 + c]);
            }
            wf[ni][t] = __builtin_bit_cast(bf16x8, ta);
            wsx[ni][t] = __builtin_bit_cast(bf16x8, tb);
        }
    }

    for (int tile = blockIdx.x; tile < ntiles; tile += gridDim.x) {
        const int n0 = tile * 32;
        __syncthreads();
        {
            const int el = tid >> 3, p = tid & 7;   // 8 threads/node, 16 cols each
            const int i = n0 + el;
            uint4* d = (uint4*)(Hs + el * 136 + p * 16);
            if (i < NN) {
                const uint4* hr = (const uint4*)(hbf + (size_t)i * 128 + p * 16);
                d[0] = hr[0]; d[1] = hr[1];
            } else {
                uint4 z = make_uint4(0, 0, 0, 0);
                d[0] = z; d[1] = z;
            }
        }
        __syncthreads();
        f32x4 af[2][2], as_[2][2];
#pragma unroll
        for (int mi = 0; mi < 2; ++mi)
#pragma unroll
            for (int ni = 0; ni < 2; ++ni) { af[mi][ni] = fzero; as_[mi][ni] = fzero; }
        {
            const int arow = llo * 136 + lhi * 8;
#pragma unroll
            for (int t = 0; t < 4; ++t) {
                bf16x8 a0 = ldfrag(Hs + arow + t * 32);
                bf16x8 a1 = ldfrag(Hs + arow + 16 * 136 + t * 32);
#pragma unroll
                for (int ni = 0; ni < 2; ++ni) {
                    af[0][ni] = MFMA(a0, wf[ni][t], af[0][ni]);
                    af[1][ni] = MFMA(a1, wf[ni][t], af[1][ni]);
                    as_[0][ni] = MFMA(a0, wsx[ni][t], as_[0][ni]);
                    as_[1][ni] = MFMA(a1, wsx[ni][t], as_[1][ni]);
                }
            }
        }
#pragma unroll
        for (int mi = 0; mi < 2; ++mi) {
#pragma unroll
            for (int ni = 0; ni < 2; ++ni) {
                const int col = wv * 32 + ni * 16 + llo;
#pragma unroll
                for (int r = 0; r < 4; ++r) {
                    const int row = mi * 16 + lhi * 4 + r;
                    const int i = n0 + row;
                    if (i < NN) {
                        Yf[(size_t)i * 128 + col] = f2bf(af[mi][ni][r] + b1r[ni]);
                        Ys[(size_t)i * 128 + col] = f2bf(as_[mi][ni][r]);
                    }
                }
            }
        }
    }
}

// ---------------- Y-based edge kernel: 2 waves, 32-edge tiles, high occupancy ----------------
// r13 structure; geometry computed inline from L2-resident cpk (no geo array).
__global__ __launch_bounds__(128, 2) void k_edge_y(
    const u16* __restrict__ Yf, const u16* __restrict__ Ys,
    const int4* __restrict__ sorted, const float4* __restrict__ cpk,
    const float* __restrict__ ef, const float* __restrict__ We1,
    const float* __restrict__ We2, const float* __restrict__ be2,
    const float* __restrict__ Wc, const float* __restrict__ bc,
    float* __restrict__ out, int NE, int ntiles) {
    __shared__ u16 Yp[32 * 136];
    __shared__ u16 M2h[32 * 136];
    __shared__ u16 Ed[32 * 32];
    __shared__ float cds[32][4];
    __shared__ int fidxs[32];

    const int tid = threadIdx.x;
    const int lane = tid & 63;
    const int wv = tid >> 6;
    const int lhi = lane >> 4, llo = lane & 15;
    const f32x4 fzero = {0.f, 0.f, 0.f, 0.f};

    for (int i = tid; i < 32 * 32; i += 128) Ed[i] = 0;

    bf16x8 w2[4][4];
    bf16x8 we[4];
    float be2r[4];
#pragma unroll
    for (int ni = 0; ni < 4; ++ni) {
        const int c = wv * 64 + ni * 16 + llo;
        be2r[ni] = be2[c];
#pragma unroll
        for (int t = 0; t < 4; ++t) {
            u16x8 tmp;
#pragma unroll
            for (int j = 0; j < 8; ++j) {
                int k = t * 32 + lhi * 8 + j;
                tmp[j] = f2bf(We2[(size_t)k * 128 + c]);
            }
            w2[ni][t] = __builtin_bit_cast(bf16x8, tmp);
        }
        u16x8 te;
#pragma unroll
        for (int j = 0; j < 8; ++j) {
            int k = lhi * 8 + j;
            float v = (k <= 16) ? We1[(size_t)(256 + k) * 128 + c] : 0.f;
            te[j] = f2bf(v);
        }
        we[ni] = __builtin_bit_cast(bf16x8, te);
    }
    __syncthreads();

    const int cpb = (ntiles + gridDim.x - 1) / gridDim.x;
    const int t0 = blockIdx.x * cpb;
    const int t1 = min(t0 + cpb, ntiles);

    for (int tile = t0; tile < t1; ++tile) {
        const int e0 = tile * 32;
        __syncthreads();  // (1) LDS reuse safety
        // ---- stage: 4 threads/edge, 32 cols (4x uint4); geometry from cpk (L2-hot) ----
        {
            const int el = tid >> 2, p = tid & 3;
            const int r = e0 + el;
            if (r < NE) {
                const int4 srec = sorted[r];
                const int f = srec.x, s = srec.y, e = srec.z;
                const uint4* yfp = (const uint4*)(Yf + (size_t)f * 128 + p * 32);
                const uint4* ysp = (const uint4*)(Ys + (size_t)s * 128 + p * 32);
                uint4* d = (uint4*)(Yp + el * 136 + p * 32);
                d[0] = addpk4(yfp[0], ysp[0]);
                d[1] = addpk4(yfp[1], ysp[1]);
                d[2] = addpk4(yfp[2], ysp[2]);
                d[3] = addpk4(yfp[3], ysp[3]);
                if (p == 0) {
                    const float4 a = cpk[f], b = cpk[s];
                    const float dx = a.x - b.x, dy = a.y - b.y, dz = a.z - b.z;
                    cds[el][0] = dx; cds[el][1] = dy; cds[el][2] = dz;
                    Ed[el * 32 + 0] = f2bf(dx * dx + dy * dy + dz * dz);
                    fidxs[el] = f;
                } else if (p == 1) {
                    const float4* ep = (const float4*)(ef + (size_t)e * 16);
                    float4 e0v = ep[0], e1v = ep[1], e2v = ep[2], e3v = ep[3];
                    u16* er = Ed + el * 32 + 1;
                    er[0] = f2bf(e0v.x); er[1] = f2bf(e0v.y); er[2] = f2bf(e0v.z); er[3] = f2bf(e0v.w);
                    er[4] = f2bf(e1v.x); er[5] = f2bf(e1v.y); er[6] = f2bf(e1v.z); er[7] = f2bf(e1v.w);
                    er[8] = f2bf(e2v.x); er[9] = f2bf(e2v.y); er[10] = f2bf(e2v.z); er[11] = f2bf(e2v.w);
                    er[12] = f2bf(e3v.x); er[13] = f2bf(e3v.y); er[14] = f2bf(e3v.z); er[15] = f2bf(e3v.w);
                }
            } else {
                uint4 z = make_uint4(0, 0, 0, 0);
                uint4* d = (uint4*)(Yp + el * 136 + p * 32);
                d[0] = z; d[1] = z; d[2] = z; d[3] = z;
                if (p == 0) {
                    fidxs[el] = -1;
                    cds[el][0] = cds[el][1] = cds[el][2] = 0.f;
                    Ed[el * 32 + 0] = 0;
                } else if (p == 1) {
                    u16* er = Ed + el * 32 + 1;
#pragma unroll
                    for (int j = 0; j < 16; ++j) er[j] = 0;
                }
            }
        }
        __syncthreads();  // (2) stage visible
        // ---- phase A: m1 = silu(eterm + Yp) in place ----
        {
            __builtin_amdgcn_s_setprio(1);
#pragma unroll
            for (int mi = 0; mi < 2; ++mi) {
                bf16x8 a = ldfrag(Ed + (mi * 16 + llo) * 32 + lhi * 8);
#pragma unroll
                for (int ni = 0; ni < 4; ++ni) {
                    f32x4 acc = MFMA(a, we[ni], fzero);
                    const int col = wv * 64 + ni * 16 + llo;
#pragma unroll
                    for (int r = 0; r < 4; ++r) {
                        const int row = mi * 16 + lhi * 4 + r;
                        float y = bf2f(Yp[row * 136 + col]);
                        Yp[row * 136 + col] = f2bf(silu_f(acc[r] + y));
                    }
                }
            }
            __builtin_amdgcn_s_setprio(0);
        }
        __syncthreads();  // (3) m1 ready
        // ---- MLP2: 32 rows, one pass ----
        {
            f32x4 acc2[2][4];
#pragma unroll
            for (int mi = 0; mi < 2; ++mi)
#pragma unroll
                for (int ni = 0; ni < 4; ++ni) acc2[mi][ni] = fzero;
            const int arow = llo * 136 + lhi * 8;
            __builtin_amdgcn_s_setprio(1);
#pragma unroll
            for (int t = 0; t < 4; ++t) {
                bf16x8 a0 = ldfrag(Yp + arow + t * 32);
                bf16x8 a1 = ldfrag(Yp + arow + 16 * 136 + t * 32);
#pragma unroll
                for (int ni = 0; ni < 4; ++ni) {
                    acc2[0][ni] = MFMA(a0, w2[ni][t], acc2[0][ni]);
                    acc2[1][ni] = MFMA(a1, w2[ni][t], acc2[1][ni]);
                }
            }
            __builtin_amdgcn_s_setprio(0);
#pragma unroll
            for (int mi = 0; mi < 2; ++mi) {
#pragma unroll
                for (int ni = 0; ni < 4; ++ni) {
                    const int col = wv * 64 + ni * 16 + llo;
#pragma unroll
                    for (int r = 0; r < 4; ++r) {
                        const int row = mi * 16 + lhi * 4 + r;
                        M2h[row * 136 + col] = f2bf(silu_f(acc2[mi][ni][r] + be2r[ni]));
                    }
                }
            }
        }
        __syncthreads();  // (4) m2 visible
        // ---- coord gate: 4 threads/edge; Wc from global (L2-hot) ----
        {
            const int el = tid >> 2, p = tid & 3;
            const u32* mr = (const u32*)(M2h + el * 136 + p * 32);
            float dot = 0.f;
#pragma unroll
            for (int i = 0; i < 16; ++i) {
                u32 w = mr[i];
                dot += bf2f((u16)(w & 0xffffu)) * Wc[p * 32 + 2 * i];
                dot += bf2f((u16)(w >> 16)) * Wc[p * 32 + 2 * i + 1];
            }
            dot += __shfl_xor(dot, 1);
            dot += __shfl_xor(dot, 2);
            if (p == 0) {
                const float sc = dot + bc[0];
                cds[el][0] *= sc; cds[el][1] *= sc; cds[el][2] *= sc;
            }
        }
        __syncthreads();  // (5) cds scaled
        // ---- segmented reductions (edges sorted by f) ----
        {
            const int col = tid;
            float sum = 0.f;
            int curf = -2;
            for (int k = 0; k < 32; ++k) {
                const int fr = fidxs[k];
                if (fr != curf) {
                    if (curf >= 0) unsafeAtomicAdd(&out[(size_t)curf * 131 + 3 + col], sum);
                    sum = 0.f; curf = fr;
                }
                sum += bf2f(M2h[k * 136 + col]);
            }
            if (curf >= 0) unsafeAtomicAdd(&out[(size_t)curf * 131 + 3 + col], sum);
        }
        if (tid < 48) {
            const int c = tid % 3;
            const int r0 = (tid / 3) * 2;
            float sum = 0.f;
            int curf = -2;
#pragma unroll
            for (int k = 0; k < 2; ++k) {
                const int rr = r0 + k;
                const int fr = fidxs[rr];
                if (fr != curf) {
                    if (curf >= 0) unsafeAtomicAdd(&out[(size_t)curf * 131 + c], sum);
                    sum = 0.f; curf = fr;
                }
                sum += cds[rr][c];
            }
            if (curf >= 0) unsafeAtomicAdd(&out[(size_t)curf * 131 + c], sum);
        }
    }
}

// ---------------- round-5 gather edge kernel (ws fallback, unchanged) ----------------
template <int USE_HBF>
__global__ __launch_bounds__(128) void k_edge_s(
    const u16* __restrict__ hbf, const float* __restrict__ nf,
    const int4* __restrict__ sorted, const float* __restrict__ ef,
    const float* __restrict__ We1, const float* __restrict__ be1,
    const float* __restrict__ We2, const float* __restrict__ be2,
    const float* __restrict__ Wc, const float* __restrict__ bc,
    float* __restrict__ out, int NE, int ntiles) {
    __shared__ u16 Xs[32 * 296];
    __shared__ float M2f[32 * 132];
    __shared__ float cds[32][4];
    __shared__ int fidxs[32];
    __shared__ float be1s[128], be2s[128], Wcs[128];
    __shared__ float bcs;

    const int tid = threadIdx.x;
    const int lane = tid & 63;
    const int wv = tid >> 6;
    const int lhi = lane >> 4, llo = lane & 15;
    const f32x4 fzero = {0.f, 0.f, 0.f, 0.f};

    be1s[tid] = be1[tid]; be2s[tid] = be2[tid]; Wcs[tid] = Wc[tid];
    if (tid == 0) bcs = bc[0];

    bf16x8 w1f[4][9];
    bf16x8 w2f[4][4];
#pragma unroll
    for (int ni = 0; ni < 4; ++ni) {
        const int c = wv * 64 + ni * 16 + llo;
#pragma unroll
        for (int t = 0; t < 9; ++t) {
            u16x8 tmp;
#pragma unroll
            for (int j = 0; j < 8; ++j) {
                int k = t * 32 + lhi * 8 + j;
                float v = (k < 273) ? We1[(size_t)k * 128 + c] : 0.f;
                tmp[j] = f2bf(v);
            }
            w1f[ni][t] = __builtin_bit_cast(bf16x8, tmp);
        }
#pragma unroll
        for (int t = 0; t < 4; ++t) {
            u16x8 tmp;
#pragma unroll
            for (int j = 0; j < 8; ++j) {
                int k = t * 32 + lhi * 8 + j;
                tmp[j] = f2bf(We2[(size_t)k * 128 + c]);
            }
            w2f[ni][t] = __builtin_bit_cast(bf16x8, tmp);
        }
    }

    const int cpb = (ntiles + gridDim.x - 1) / gridDim.x;
    const int t0 = blockIdx.x * cpb;
    const int t1 = min(t0 + cpb, ntiles);

    for (int tile = t0; tile < t1; ++tile) {
        const int e0 = tile * 32;
        __syncthreads();
        {
            const int el = tid >> 2, p = tid & 3;
            const int r = e0 + el;
            if (r < NE) {
                const int4 srec = sorted[r];
                const int f = srec.x, s = srec.y, e = srec.z;
                if (USE_HBF) {
                    const uint4* hf = (const uint4*)(hbf + (size_t)f * 128);
                    const uint4* hs = (const uint4*)(hbf + (size_t)s * 128);
                    uint4* df = (uint4*)(Xs + el * 296 + p * 32);
                    df[0] = hf[p * 4 + 0]; df[1] = hf[p * 4 + 1];
                    df[2] = hf[p * 4 + 2]; df[3] = hf[p * 4 + 3];
                    uint4* ds2 = (uint4*)(Xs + el * 296 + 128 + p * 32);
                    ds2[0] = hs[p * 4 + 0]; ds2[1] = hs[p * 4 + 1];
                    ds2[2] = hs[p * 4 + 2]; ds2[3] = hs[p * 4 + 3];
                } else {
                    const float* src = (p < 2) ? (nf + (size_t)f * 131 + 3 + p * 64)
                                               : (nf + (size_t)s * 131 + 3 + (p - 2) * 64);
                    u16* dst = Xs + el * 296 + p * 64;
#pragma unroll
                    for (int q = 0; q < 64; q += 8) {
                        u16x8 v;
#pragma unroll
                        for (int j = 0; j < 8; ++j) v[j] = f2bf(src[q + j]);
                        *(u16x8*)(dst + q) = v;
                    }
                }
                if (p == 0) {
                    const float* ep = ef + (size_t)e * 16;
                    u16* xr = Xs + el * 296;
#pragma unroll
                    for (int j = 0; j < 16; ++j) xr[257 + j] = f2bf(ep[j]);
                } else if (p == 1) {
                    float ax = nf[(size_t)f * 131 + 0], ay = nf[(size_t)f * 131 + 1], az = nf[(size_t)f * 131 + 2];
                    float bx = nf[(size_t)s * 131 + 0], by = nf[(size_t)s * 131 + 1], bz = nf[(size_t)s * 131 + 2];
                    float dx = ax - bx, dy = ay - by, dz = az - bz;
                    cds[el][0] = dx; cds[el][1] = dy; cds[el][2] = dz;
                    Xs[el * 296 + 256] = f2bf(dx * dx + dy * dy + dz * dz);
                    fidxs[el] = f;
                } else if (p == 2) {
                    u16* xr = Xs + el * 296;
#pragma unroll
                    for (int j = 273; j < 288; ++j) xr[j] = 0;
                }
            } else {
                u16* xr = Xs + el * 296;
#pragma unroll
                for (int j = 0; j < 72; ++j) xr[p * 72 + j] = 0;
                if (p == 1) { fidxs[el] = -1; cds[el][0] = cds[el][1] = cds[el][2] = 0.f; }
            }
        }
        __syncthreads();
        f32x4 acc[2][4];
#pragma unroll
        for (int mi = 0; mi < 2; ++mi)
#pragma unroll
            for (int ni = 0; ni < 4; ++ni) acc[mi][ni] = fzero;
        {
            const int arow = llo * 296 + lhi * 8;
            __builtin_amdgcn_s_setprio(1);
#pragma unroll
            for (int t = 0; t < 9; ++t) {
                bf16x8 a0 = ldfrag(Xs + arow + t * 32);
                bf16x8 a1 = ldfrag(Xs + arow + 16 * 296 + t * 32);
#pragma unroll
                for (int ni = 0; ni < 4; ++ni) {
                    acc[0][ni] = MFMA(a0, w1f[ni][t], acc[0][ni]);
                    acc[1][ni] = MFMA(a1, w1f[ni][t], acc[1][ni]);
                }
            }
            __builtin_amdgcn_s_setprio(0);
        }
        __syncthreads();
        u16* ms = Xs;
#pragma unroll
        for (int mi = 0; mi < 2; ++mi) {
#pragma unroll
            for (int ni = 0; ni < 4; ++ni) {
                const int col = wv * 64 + ni * 16 + llo;
                const float b = be1s[col];
#pragma unroll
                for (int r = 0; r < 4; ++r) {
                    const int row = mi * 16 + lhi * 4 + r;
                    ms[row * 136 + col] = f2bf(silu_f(acc[mi][ni][r] + b));
                }
            }
        }
        __syncthreads();
        f32x4 acc2[2][4];
#pragma unroll
        for (int mi = 0; mi < 2; ++mi)
#pragma unroll
            for (int ni = 0; ni < 4; ++ni) acc2[mi][ni] = fzero;
        {
            const int arow = llo * 136 + lhi * 8;
            __builtin_amdgcn_s_setprio(1);
#pragma unroll
            for (int t = 0; t < 4; ++t) {
                bf16x8 a0 = ldfrag(ms + arow + t * 32);
                bf16x8 a1 = ldfrag(ms + arow + 16 * 136 + t * 32);
#pragma unroll
                for (int ni = 0; ni < 4; ++ni) {
                    acc2[0][ni] = MFMA(a0, w2f[ni][t], acc2[0][ni]);
                    acc2[1][ni] = MFMA(a1, w2f[ni][t], acc2[1][ni]);
                }
            }
            __builtin_amdgcn_s_setprio(0);
        }
#pragma unroll
        for (int mi = 0; mi < 2; ++mi) {
#pragma unroll
            for (int ni = 0; ni < 4; ++ni) {
                const int col = wv * 64 + ni * 16 + llo;
                const float b = be2s[col];
#pragma unroll
                for (int r = 0; r < 4; ++r) {
                    const int row = mi * 16 + lhi * 4 + r;
                    M2f[row * 132 + col] = silu_f(acc2[mi][ni][r] + b);
                }
            }
        }
        __syncthreads();
        {
            const int el = tid >> 2, p = tid & 3;
            const float* mrow = M2f + el * 132 + p * 32;
            float dot = 0.f;
#pragma unroll
            for (int i = 0; i < 32; ++i) dot += mrow[i] * Wcs[p * 32 + i];
            dot += __shfl_xor(dot, 1);
            dot += __shfl_xor(dot, 2);
            if (p == 0) {
                const float sc = dot + bcs;
                cds[el][0] *= sc; cds[el][1] *= sc; cds[el][2] *= sc;
            }
        }
        __syncthreads();
        {
            const int col = tid;
            float sum = 0.f;
            int curf = -2;
            for (int k = 0; k < 32; ++k) {
                const int fr = fidxs[k];
                if (fr != curf) {
                    if (curf >= 0) unsafeAtomicAdd(&out[(size_t)curf * 131 + 3 + col], sum);
                    sum = 0.f; curf = fr;
                }
                sum += M2f[k * 132 + col];
            }
            if (curf >= 0) unsafeAtomicAdd(&out[(size_t)curf * 131 + 3 + col], sum);
        }
        if (tid < 48) {
            const int c = tid % 3;
            const int r0 = (tid / 3) * 2;
            float sum = 0.f;
            int curf = -2;
#pragma unroll
            for (int k = 0; k < 2; ++k) {
                const int rr = r0 + k;
                const int fr = fidxs[rr];
                if (fr != curf) {
                    if (curf >= 0) unsafeAtomicAdd(&out[(size_t)curf * 131 + c], sum);
                    sum = 0.f; curf = fr;
                }
                sum += cds[rr][c];
            }
            if (curf >= 0) unsafeAtomicAdd(&out[(size_t)curf * 131 + c], sum);
        }
    }
}

// ---------------- node kernel: 4 waves x 32 cols, high occupancy ----------------
template <int USE_HBF>
__global__ __launch_bounds__(256, 2) void k_node(
    const u16* __restrict__ hbf, const float* __restrict__ nf,
    const int* __restrict__ cnt,
    const float* __restrict__ Wn1, const float* __restrict__ bn1,
    const float* __restrict__ Wn2, const float* __restrict__ bn2,
    float* __restrict__ out, int NN, int ntiles) {
    __shared__ u16 Xs[32 * 264];

    const int tid = threadIdx.x;
    const int lane = tid & 63;
    const int wv = tid >> 6;
    const int lhi = lane >> 4, llo = lane & 15;
    const f32x4 fzero = {0.f, 0.f, 0.f, 0.f};

    bf16x8 w1f[2][8];
    bf16x8 w2f[2][4];
    float b1r[2], b2r[2];
#pragma unroll
    for (int ni = 0; ni < 2; ++ni) {
        const int c = wv * 32 + ni * 16 + llo;
        b1r[ni] = bn1[c]; b2r[ni] = bn2[c];
#pragma unroll
        for (int t = 0; t < 8; ++t) {
            u16x8 tmp;
#pragma unroll
            for (int j = 0; j < 8; ++j) {
                int k = t * 32 + lhi * 8 + j;
                tmp[j] = f2bf(Wn1[(size_t)k * 128 + c]);
            }
            w1f[ni][t] = __builtin_bit_cast(bf16x8, tmp);
        }
#pragma unroll
        for (int t = 0; t < 4; ++t) {
            u16x8 tmp;
#pragma unroll
            for (int j = 0; j < 8; ++j) {
                int k = t * 32 + lhi * 8 + j;
                tmp[j] = f2bf(Wn2[(size_t)k * 128 + c]);
            }
            w2f[ni][t] = __builtin_bit_cast(bf16x8, tmp);
        }
    }

    for (int tile = blockIdx.x; tile < ntiles; tile += gridDim.x) {
        const int n0 = tile * 32;
        __syncthreads();
        {
            const int el = tid >> 3, p = tid & 7;
            const int i = n0 + el;
            if (i < NN) {
                if (p < 4) {
                    u16* dst = Xs + el * 264 + p * 32;
                    if (USE_HBF) {
                        const uint4* hr = (const uint4*)(hbf + (size_t)i * 128 + p * 32);
                        uint4* d = (uint4*)dst;
                        d[0] = hr[0]; d[1] = hr[1]; d[2] = hr[2]; d[3] = hr[3];
                    } else {
                        const float* src = nf + (size_t)i * 131 + 3 + p * 32;
#pragma unroll
                        for (int q = 0; q < 32; q += 8) {
                            u16x8 v;
#pragma unroll
                            for (int j = 0; j < 8; ++j) v[j] = f2bf(src[q + j]);
                            *(u16x8*)(dst + q) = v;
                        }
                    }
                } else {
                    const float* nb = out + (size_t)i * 131 + 3 + (p - 4) * 32;
                    u16* dst = Xs + el * 264 + 128 + (p - 4) * 32;
#pragma unroll
                    for (int q = 0; q < 32; q += 8) {
                        u16x8 v;
#pragma unroll
                        for (int j = 0; j < 8; ++j) v[j] = f2bf(nb[q + j]);
                        *(u16x8*)(dst + q) = v;
                    }
                }
            } else {
                uint4 z = make_uint4(0, 0, 0, 0);
                uint4* d = (uint4*)(Xs + el * 264 + p * 32);
                d[0] = z; d[1] = z; d[2] = z; d[3] = z;
            }
        }
        __syncthreads();
        f32x4 acc[2][2];
#pragma unroll
        for (int mi = 0; mi < 2; ++mi)
#pragma unroll
            for (int ni = 0; ni < 2; ++ni) acc[mi][ni] = fzero;
        {
            const int arow = llo * 264 + lhi * 8;
            __builtin_amdgcn_s_setprio(1);
#pragma unroll
            for (int t = 0; t < 8; ++t) {
                bf16x8 a0 = ldfrag(Xs + arow + t * 32);
                bf16x8 a1 = ldfrag(Xs + arow + 16 * 264 + t * 32);
#pragma unroll
                for (int ni = 0; ni < 2; ++ni) {
                    acc[0][ni] = MFMA(a0, w1f[ni][t], acc[0][ni]);
                    acc[1][ni] = MFMA(a1, w1f[ni][t], acc[1][ni]);
                }
            }
            __builtin_amdgcn_s_setprio(0);
        }
        __syncthreads();
        u16* ms = Xs;
#pragma unroll
        for (int mi = 0; mi < 2; ++mi) {
#pragma unroll
            for (int ni = 0; ni < 2; ++ni) {
                const int col = wv * 32 + ni * 16 + llo;
#pragma unroll
                for (int r = 0; r < 4; ++r) {
                    const int row = mi * 16 + lhi * 4 + r;
                    ms[row * 136 + col] = f2bf(silu_f(acc[mi][ni][r] + b1r[ni]));
                }
            }
        }
        __syncthreads();
        f32x4 acc2[2][2];
#pragma unroll
        for (int mi = 0; mi < 2; ++mi)
#pragma unroll
            for (int ni = 0; ni < 2; ++ni) acc2[mi][ni] = fzero;
        {
            const int arow = llo * 136 + lhi * 8;
            __builtin_amdgcn_s_setprio(1);
#pragma unroll
            for (int t = 0; t < 4; ++t) {
                bf16x8 a0 = ldfrag(ms + arow + t * 32);
                bf16x8 a1 = ldfrag(ms + arow + 16 * 136 + t * 32);
#pragma unroll
                for (int ni = 0; ni < 2; ++ni) {
                    acc2[0][ni] = MFMA(a0, w2f[ni][t], acc2[0][ni]);
                    acc2[1][ni] = MFMA(a1, w2f[ni][t], acc2[1][ni]);
                }
            }
            __builtin_amdgcn_s_setprio(0);
        }
#pragma unroll
        for (int mi = 0; mi < 2; ++mi) {
#pragma unroll
            for (int ni = 0; ni < 2; ++ni) {
                const int col = wv * 32 + ni * 16 + llo;
#pragma unroll
                for (int r = 0; r < 4; ++r) {
                    const int row = mi * 16 + lhi * 4 + r;
                    const int i = n0 + row;
                    if (i < NN) out[(size_t)i * 131 + 3 + col] = acc2[mi][ni][r] + b2r[ni];
                }
            }
        }
        {
            const int el = tid >> 3, c = tid & 7;
            const int i = n0 + el;
            if (c < 3 && i < NN) {
                float cc = out[(size_t)i * 131 + c];
                out[(size_t)i * 131 + c] =
                    nf[(size_t)i * 131 + c] + cc / fmaxf((float)cnt[i], 1.f);
            }
        }
    }
}

extern "C" void kernel_launch(void* const* d_in, const int* in_sizes, int n_in,
                              void* d_out, int out_size, void* d_ws, size_t ws_size,
                              hipStream_t stream) {
    const float* nf = (const float*)d_in[0];
    const int* ei = (const int*)d_in[1];
    const float* ef = (const float*)d_in[2];
    const float* We1 = (const float*)d_in[3];
    const float* be1 = (const float*)d_in[4];
    const float* We2 = (const float*)d_in[5];
    const float* be2 = (const float*)d_in[6];
    const float* Wc = (const float*)d_in[7];
    const float* bc = (const float*)d_in[8];
    const float* Wn1 = (const float*)d_in[9];
    const float* bn1 = (const float*)d_in[10];
    const float* Wn2 = (const float*)d_in[11];
    const float* bn2 = (const float*)d_in[12];

    const int NN = in_sizes[0] / 131;
    const int NE = in_sizes[2] / 16;
    float* out = (float*)d_out;
    char* ws = (char*)d_ws;

    // ws: [cnt][cursor][bsum pad][sorted NE*16][hbf NN*256][cpk NN*16][Yf NN*256][Ys NN*256]
    const size_t szN = (size_t)NN * 4;
    const size_t o_cnt = 0;
    const size_t o_cur = szN;
    const size_t o_bsum = 2 * szN;
    const size_t o_sorted = (2 * szN + 4096 + 15) & ~(size_t)15;
    const size_t o_hbf = o_sorted + (size_t)NE * 16;
    const size_t o_cpk = o_hbf + (size_t)NN * 256;
    const size_t o_yf = o_cpk + (size_t)NN * 16;
    const size_t o_ys = o_yf + (size_t)NN * 256;
    const size_t need_core = o_cpk;
    const size_t need_y = o_ys + (size_t)NN * 256;

    hipMemsetAsync(d_out, 0, (size_t)out_size * 4, stream);
    hipMemsetAsync(ws + o_cnt, 0, szN, stream);

    int* cnt = (int*)(ws + o_cnt);
    const int ntiles_n = (NN + 31) / 32;

    if (ws_size >= need_core) {
        int* cursor = (int*)(ws + o_cur);
        int* bsum = (int*)(ws + o_bsum);
        int4* sorted = (int4*)(ws + o_sorted);
        u16* hbf = (u16*)(ws + o_hbf);
        float4* cpk = (float4*)(ws + o_cpk);
        u16* Yf = (u16*)(ws + o_yf);
        u16* Ys = (u16*)(ws + o_ys);
        const bool use_y = ws_size >= need_y;

        k_prep<<<(NN * 16 + 255) / 256, 256, 0, stream>>>(nf, hbf, use_y ? cpk : nullptr, NN);
        k_hist<<<(NE + 255) / 256, 256, 0, stream>>>(ei, cnt, NE);
        const int NB = (NN + 1023) / 1024;
        k_scanA<<<NB, 256, 0, stream>>>(cnt, cursor, bsum, NN);
        k_scanB<<<1, 64, 0, stream>>>(bsum, NB);
        k_scanC<<<(NN + 255) / 256, 256, 0, stream>>>(cursor, bsum, NN);
        k_scatter<<<(NE + 255) / 256, 256, 0, stream>>>(ei, ei + NE, cursor, sorted, NE);

        if (use_y) {
            k_ymm<<<ntiles_n, 256, 0, stream>>>(hbf, We1, be1, Yf, Ys, NN, ntiles_n);
            const int ntiles_e = (NE + 31) / 32;
            k_edge_y<<<2048, 128, 0, stream>>>(Yf, Ys, sorted, cpk, ef, We1,
                                               We2, be2, Wc, bc, out, NE, ntiles_e);
        } else {
            const int ntiles_e = (NE + 31) / 32;
            k_edge_s<1><<<1024, 128, 0, stream>>>(hbf, nf, sorted, ef,
                                                  We1, be1, We2, be2, Wc, bc, out, NE, ntiles_e);
        }
        k_node<1><<<ntiles_n, 256, 0, stream>>>(hbf, nf, cnt, Wn1, bn1, Wn2, bn2, out, NN, ntiles_n);
    } else {
        int* cursor = (int*)(ws + o_cur);
        int* bsum = (int*)(ws + o_bsum);
        int4* sorted = (int4*)(ws + o_sorted);
        const bool have_sort = ws_size >= o_hbf;
        k_hist<<<(NE + 255) / 256, 256, 0, stream>>>(ei, cnt, NE);
        if (have_sort) {
            const int NB = (NN + 1023) / 1024;
            k_scanA<<<NB, 256, 0, stream>>>(cnt, cursor, bsum, NN);
            k_scanB<<<1, 64, 0, stream>>>(bsum, NB);
            k_scanC<<<(NN + 255) / 256, 256, 0, stream>>>(cursor, bsum, NN);
            k_scatter<<<(NE + 255) / 256, 256, 0, stream>>>(ei, ei + NE, cursor, sorted, NE);
            const int ntiles_e = (NE + 31) / 32;
            k_edge_s<0><<<1024, 128, 0, stream>>>(nullptr, nf, sorted, ef,
                                                  We1, be1, We2, be2, Wc, bc, out, NE, ntiles_e);
        }
        k_node<0><<<ntiles_n, 256, 0, stream>>>(nullptr, nf, cnt, Wn1, bn1, Wn2, bn2, out, NN, ntiles_n);
    }
}

// Round 16
// 377.226 us; speedup vs baseline: 1.0329x; 1.0329x over previous
//
#include <hip/hip_runtime.h>

typedef unsigned short u16;
typedef unsigned int u32;
typedef __bf16 bf16x8 __attribute__((ext_vector_type(8)));
typedef u16 u16x8 __attribute__((ext_vector_type(8)));
typedef float f32x4 __attribute__((ext_vector_type(4)));

#define MFMA(a, b, c) __builtin_amdgcn_mfma_f32_16x16x32_bf16(a, b, c, 0, 0, 0)

__device__ __forceinline__ u16 f2bf(float x) {
    u32 u = __builtin_bit_cast(u32, x);
    u32 r = (u + 0x7FFFu + ((u >> 16) & 1u)) >> 16;
    return (u16)r;
}
__device__ __forceinline__ float bf2f(u16 h) {
    u32 u = ((u32)h) << 16;
    return __builtin_bit_cast(float, u);
}
__device__ __forceinline__ u32 addpk(u32 a, u32 b) {
    float lo = bf2f((u16)(a & 0xffffu)) + bf2f((u16)(b & 0xffffu));
    float hi = bf2f((u16)(a >> 16)) + bf2f((u16)(b >> 16));
    return (u32)f2bf(lo) | ((u32)f2bf(hi) << 16);
}
__device__ __forceinline__ uint4 addpk4(uint4 a, uint4 b) {
    uint4 o;
    o.x = addpk(a.x, b.x); o.y = addpk(a.y, b.y);
    o.z = addpk(a.z, b.z); o.w = addpk(a.w, b.w);
    return o;
}
__device__ __forceinline__ float silu_f(float x) {
    return x * __builtin_amdgcn_rcpf(1.f + __expf(-x));
}
__device__ __forceinline__ bf16x8 ldfrag(const u16* p) {
    return __builtin_bit_cast(bf16x8, *(const u16x8*)p);
}

// ---------------- h -> bf16 table (+ compact coords table) ----------------
__global__ void k_prep(const float* __restrict__ nf, u16* __restrict__ hbf,
                       float4* __restrict__ cpk, int NN) {
    int idx = blockIdx.x * 256 + threadIdx.x;
    int i = idx >> 4, p = idx & 15;
    if (i >= NN) return;
    const float* src = nf + (size_t)i * 131 + 3 + p * 8;
    u16x8 v;
#pragma unroll
    for (int j = 0; j < 8; ++j) v[j] = f2bf(src[j]);
    *(u16x8*)(hbf + (size_t)i * 128 + p * 8) = v;
    if (cpk && p == 0) {
        const float* c = nf + (size_t)i * 131;
        cpk[i] = make_float4(c[0], c[1], c[2], 0.f);
    }
}

// ---------------- degree histogram ----------------
__global__ void k_hist(const int* __restrict__ first, int* __restrict__ cnt, int NE) {
    int e = blockIdx.x * 256 + threadIdx.x;
    if (e < NE) atomicAdd(&cnt[first[e]], 1);
}

// ---------------- counting-sort: scan + scatter (+fused geo) ----------------
__global__ void k_scanA(const int* __restrict__ cnt, int* __restrict__ cursor,
                        int* __restrict__ bsum, int NN) {
    __shared__ int wsum[4];
    const int t = threadIdx.x;
    const int base = blockIdx.x * 1024 + t * 4;
    int v0 = base + 0 < NN ? cnt[base + 0] : 0;
    int v1 = base + 1 < NN ? cnt[base + 1] : 0;
    int v2 = base + 2 < NN ? cnt[base + 2] : 0;
    int v3 = base + 3 < NN ? cnt[base + 3] : 0;
    const int s = v0 + v1 + v2 + v3;
    const int lane = t & 63, w = t >> 6;
    int x = s;
#pragma unroll
    for (int d = 1; d < 64; d <<= 1) {
        int y = __shfl_up(x, d);
        if (lane >= d) x += y;
    }
    if (lane == 63) wsum[w] = x;
    __syncthreads();
    int wbase = 0;
    for (int k = 0; k < w; ++k) wbase += wsum[k];
    int run = wbase + x - s;
    if (base + 0 < NN) cursor[base + 0] = run; run += v0;
    if (base + 1 < NN) cursor[base + 1] = run; run += v1;
    if (base + 2 < NN) cursor[base + 2] = run; run += v2;
    if (base + 3 < NN) cursor[base + 3] = run;
    if (t == 255) bsum[blockIdx.x] = wbase + x;
}

__global__ void k_scanB(int* bsum, int NB) {
    if (threadIdx.x == 0 && blockIdx.x == 0) {
        int run = 0;
        for (int b = 0; b < NB; ++b) { int t = bsum[b]; bsum[b] = run; run += t; }
    }
}

__global__ void k_scanC(int* __restrict__ cursor, const int* __restrict__ bsum, int NN) {
    int i = blockIdx.x * 256 + threadIdx.x;
    if (i < NN) cursor[i] += bsum[i >> 10];
}

__global__ void k_scatter(const int* __restrict__ first, const int* __restrict__ second,
                          int* __restrict__ cursor, int4* __restrict__ sorted,
                          const float4* __restrict__ cpk, float4* __restrict__ geo, int NE) {
    int e = blockIdx.x * 256 + threadIdx.x;
    if (e < NE) {
        int f = first[e], s = second[e];
        int pos = atomicAdd(&cursor[f], 1);
        sorted[pos] = make_int4(f, s, e, 0);
        if (geo) {
            float4 a = cpk[f], b = cpk[s];
            float dx = a.x - b.x, dy = a.y - b.y, dz = a.z - b.z;
            geo[pos] = make_float4(dx, dy, dz, dx * dx + dy * dy + dz * dz);
        }
    }
}

// ---------------- Y precompute (4 waves x 32 cols, high occupancy) ----------------
// Yf = h@We1[0:128]+be1, Ys = h@We1[128:256]. Weights 64 VGPR/wave.
__global__ __launch_bounds__(256, 2) void k_ymm(
    const u16* __restrict__ hbf, const float* __restrict__ We1, const float* __restrict__ be1,
    u16* __restrict__ Yf, u16* __restrict__ Ys, int NN, int ntiles) {
    __shared__ u16 Hs[32 * 136];
    const int tid = threadIdx.x;
    const int lane = tid & 63;
    const int wv = tid >> 6;          // 0..3, owns cols [wv*32, wv*32+32)
    const int lhi = lane >> 4, llo = lane & 15;
    const f32x4 fzero = {0.f, 0.f, 0.f, 0.f};

    bf16x8 wf[2][4], wsx[2][4];
    float b1r[2];
#pragma unroll
    for (int ni = 0; ni < 2; ++ni) {
        const int c = wv * 32 + ni * 16 + llo;
        b1r[ni] = be1[c];
#pragma unroll
        for (int t = 0; t < 4; ++t) {
            u16x8 ta, tb;
#pragma unroll
            for (int j = 0; j < 8; ++j) {
                int k = t * 32 + lhi * 8 + j;
                ta[j] = f2bf(We1[(size_t)k * 128 + c]);
                tb[j] = f2bf(We1[(size_t)(128 + k) * 128 + c]);
            }
            wf[ni][t] = __builtin_bit_cast(bf16x8, ta);
            wsx[ni][t] = __builtin_bit_cast(bf16x8, tb);
        }
    }

    for (int tile = blockIdx.x; tile < ntiles; tile += gridDim.x) {
        const int n0 = tile * 32;
        __syncthreads();
        {
            const int el = tid >> 3, p = tid & 7;   // 8 threads/node, 16 cols each
            const int i = n0 + el;
            uint4* d = (uint4*)(Hs + el * 136 + p * 16);
            if (i < NN) {
                const uint4* hr = (const uint4*)(hbf + (size_t)i * 128 + p * 16);
                d[0] = hr[0]; d[1] = hr[1];
            } else {
                uint4 z = make_uint4(0, 0, 0, 0);
                d[0] = z; d[1] = z;
            }
        }
        __syncthreads();
        f32x4 af[2][2], as_[2][2];
#pragma unroll
        for (int mi = 0; mi < 2; ++mi)
#pragma unroll
            for (int ni = 0; ni < 2; ++ni) { af[mi][ni] = fzero; as_[mi][ni] = fzero; }
        {
            const int arow = llo * 136 + lhi * 8;
#pragma unroll
            for (int t = 0; t < 4; ++t) {
                bf16x8 a0 = ldfrag(Hs + arow + t * 32);
                bf16x8 a1 = ldfrag(Hs + arow + 16 * 136 + t * 32);
#pragma unroll
                for (int ni = 0; ni < 2; ++ni) {
                    af[0][ni] = MFMA(a0, wf[ni][t], af[0][ni]);
                    af[1][ni] = MFMA(a1, wf[ni][t], af[1][ni]);
                    as_[0][ni] = MFMA(a0, wsx[ni][t], as_[0][ni]);
                    as_[1][ni] = MFMA(a1, wsx[ni][t], as_[1][ni]);
                }
            }
        }
#pragma unroll
        for (int mi = 0; mi < 2; ++mi) {
#pragma unroll
            for (int ni = 0; ni < 2; ++ni) {
                const int col = wv * 32 + ni * 16 + llo;
#pragma unroll
                for (int r = 0; r < 4; ++r) {
                    const int row = mi * 16 + lhi * 4 + r;
                    const int i = n0 + row;
                    if (i < NN) {
                        Yf[(size_t)i * 128 + col] = f2bf(af[mi][ni][r] + b1r[ni]);
                        Ys[(size_t)i * 128 + col] = f2bf(as_[mi][ni][r]);
                    }
                }
            }
        }
    }
}

// ---------------- Y-based edge kernel (r13): 2 waves, 32-edge tiles, high occupancy ----------------
__global__ __launch_bounds__(128, 2) void k_edge_y(
    const u16* __restrict__ Yf, const u16* __restrict__ Ys,
    const int4* __restrict__ sorted, const float4* __restrict__ geo,
    const float* __restrict__ ef, const float* __restrict__ We1,
    const float* __restrict__ We2, const float* __restrict__ be2,
    const float* __restrict__ Wc, const float* __restrict__ bc,
    float* __restrict__ out, int NE, int ntiles) {
    __shared__ u16 Yp[32 * 136];
    __shared__ u16 M2h[32 * 136];
    __shared__ u16 Ed[32 * 32];
    __shared__ float cds[32][4];
    __shared__ int fidxs[32];

    const int tid = threadIdx.x;
    const int lane = tid & 63;
    const int wv = tid >> 6;
    const int lhi = lane >> 4, llo = lane & 15;
    const f32x4 fzero = {0.f, 0.f, 0.f, 0.f};

    for (int i = tid; i < 32 * 32; i += 128) Ed[i] = 0;

    bf16x8 w2[4][4];
    bf16x8 we[4];
    float be2r[4];
#pragma unroll
    for (int ni = 0; ni < 4; ++ni) {
        const int c = wv * 64 + ni * 16 + llo;
        be2r[ni] = be2[c];
#pragma unroll
        for (int t = 0; t < 4; ++t) {
            u16x8 tmp;
#pragma unroll
            for (int j = 0; j < 8; ++j) {
                int k = t * 32 + lhi * 8 + j;
                tmp[j] = f2bf(We2[(size_t)k * 128 + c]);
            }
            w2[ni][t] = __builtin_bit_cast(bf16x8, tmp);
        }
        u16x8 te;
#pragma unroll
        for (int j = 0; j < 8; ++j) {
            int k = lhi * 8 + j;
            float v = (k <= 16) ? We1[(size_t)(256 + k) * 128 + c] : 0.f;
            te[j] = f2bf(v);
        }
        we[ni] = __builtin_bit_cast(bf16x8, te);
    }
    __syncthreads();

    const int cpb = (ntiles + gridDim.x - 1) / gridDim.x;
    const int t0 = blockIdx.x * cpb;
    const int t1 = min(t0 + cpb, ntiles);

    for (int tile = t0; tile < t1; ++tile) {
        const int e0 = tile * 32;
        __syncthreads();
        {
            const int el = tid >> 2, p = tid & 3;
            const int r = e0 + el;
            if (r < NE) {
                const int4 srec = sorted[r];
                const int f = srec.x, s = srec.y, e = srec.z;
                const uint4* yfp = (const uint4*)(Yf + (size_t)f * 128 + p * 32);
                const uint4* ysp = (const uint4*)(Ys + (size_t)s * 128 + p * 32);
                uint4* d = (uint4*)(Yp + el * 136 + p * 32);
                d[0] = addpk4(yfp[0], ysp[0]);
                d[1] = addpk4(yfp[1], ysp[1]);
                d[2] = addpk4(yfp[2], ysp[2]);
                d[3] = addpk4(yfp[3], ysp[3]);
                if (p == 0) {
                    const float4 g = geo[r];
                    cds[el][0] = g.x; cds[el][1] = g.y; cds[el][2] = g.z;
                    Ed[el * 32 + 0] = f2bf(g.w);
                    fidxs[el] = f;
                } else if (p == 1) {
                    const float4* ep = (const float4*)(ef + (size_t)e * 16);
                    float4 e0v = ep[0], e1v = ep[1], e2v = ep[2], e3v = ep[3];
                    u16* er = Ed + el * 32 + 1;
                    er[0] = f2bf(e0v.x); er[1] = f2bf(e0v.y); er[2] = f2bf(e0v.z); er[3] = f2bf(e0v.w);
                    er[4] = f2bf(e1v.x); er[5] = f2bf(e1v.y); er[6] = f2bf(e1v.z); er[7] = f2bf(e1v.w);
                    er[8] = f2bf(e2v.x); er[9] = f2bf(e2v.y); er[10] = f2bf(e2v.z); er[11] = f2bf(e2v.w);
                    er[12] = f2bf(e3v.x); er[13] = f2bf(e3v.y); er[14] = f2bf(e3v.z); er[15] = f2bf(e3v.w);
                }
            } else {
                uint4 z = make_uint4(0, 0, 0, 0);
                uint4* d = (uint4*)(Yp + el * 136 + p * 32);
                d[0] = z; d[1] = z; d[2] = z; d[3] = z;
                if (p == 0) {
                    fidxs[el] = -1;
                    cds[el][0] = cds[el][1] = cds[el][2] = 0.f;
                    Ed[el * 32 + 0] = 0;
                } else if (p == 1) {
                    u16* er = Ed + el * 32 + 1;
#pragma unroll
                    for (int j = 0; j < 16; ++j) er[j] = 0;
                }
            }
        }
        __syncthreads();
        {
            __builtin_amdgcn_s_setprio(1);
#pragma unroll
            for (int mi = 0; mi < 2; ++mi) {
                bf16x8 a = ldfrag(Ed + (mi * 16 + llo) * 32 + lhi * 8);
#pragma unroll
                for (int ni = 0; ni < 4; ++ni) {
                    f32x4 acc = MFMA(a, we[ni], fzero);
                    const int col = wv * 64 + ni * 16 + llo;
#pragma unroll
                    for (int r = 0; r < 4; ++r) {
                        const int row = mi * 16 + lhi * 4 + r;
                        float y = bf2f(Yp[row * 136 + col]);
                        Yp[row * 136 + col] = f2bf(silu_f(acc[r] + y));
                    }
                }
            }
            __builtin_amdgcn_s_setprio(0);
        }
        __syncthreads();
        {
            f32x4 acc2[2][4];
#pragma unroll
            for (int mi = 0; mi < 2; ++mi)
#pragma unroll
                for (int ni = 0; ni < 4; ++ni) acc2[mi][ni] = fzero;
            const int arow = llo * 136 + lhi * 8;
            __builtin_amdgcn_s_setprio(1);
#pragma unroll
            for (int t = 0; t < 4; ++t) {
                bf16x8 a0 = ldfrag(Yp + arow + t * 32);
                bf16x8 a1 = ldfrag(Yp + arow + 16 * 136 + t * 32);
#pragma unroll
                for (int ni = 0; ni < 4; ++ni) {
                    acc2[0][ni] = MFMA(a0, w2[ni][t], acc2[0][ni]);
                    acc2[1][ni] = MFMA(a1, w2[ni][t], acc2[1][ni]);
                }
            }
            __builtin_amdgcn_s_setprio(0);
#pragma unroll
            for (int mi = 0; mi < 2; ++mi) {
#pragma unroll
                for (int ni = 0; ni < 4; ++ni) {
                    const int col = wv * 64 + ni * 16 + llo;
#pragma unroll
                    for (int r = 0; r < 4; ++r) {
                        const int row = mi * 16 + lhi * 4 + r;
                        M2h[row * 136 + col] = f2bf(silu_f(acc2[mi][ni][r] + be2r[ni]));
                    }
                }
            }
        }
        __syncthreads();
        {
            const int el = tid >> 2, p = tid & 3;
            const u32* mr = (const u32*)(M2h + el * 136 + p * 32);
            float dot = 0.f;
#pragma unroll
            for (int i = 0; i < 16; ++i) {
                u32 w = mr[i];
                dot += bf2f((u16)(w & 0xffffu)) * Wc[p * 32 + 2 * i];
                dot += bf2f((u16)(w >> 16)) * Wc[p * 32 + 2 * i + 1];
            }
            dot += __shfl_xor(dot, 1);
            dot += __shfl_xor(dot, 2);
            if (p == 0) {
                const float sc = dot + bc[0];
                cds[el][0] *= sc; cds[el][1] *= sc; cds[el][2] *= sc;
            }
        }
        __syncthreads();
        {
            const int col = tid;
            float sum = 0.f;
            int curf = -2;
            for (int k = 0; k < 32; ++k) {
                const int fr = fidxs[k];
                if (fr != curf) {
                    if (curf >= 0) unsafeAtomicAdd(&out[(size_t)curf * 131 + 3 + col], sum);
                    sum = 0.f; curf = fr;
                }
                sum += bf2f(M2h[k * 136 + col]);
            }
            if (curf >= 0) unsafeAtomicAdd(&out[(size_t)curf * 131 + 3 + col], sum);
        }
        if (tid < 48) {
            const int c = tid % 3;
            const int r0 = (tid / 3) * 2;
            float sum = 0.f;
            int curf = -2;
#pragma unroll
            for (int k = 0; k < 2; ++k) {
                const int rr = r0 + k;
                const int fr = fidxs[rr];
                if (fr != curf) {
                    if (curf >= 0) unsafeAtomicAdd(&out[(size_t)curf * 131 + c], sum);
                    sum = 0.f; curf = fr;
                }
                sum += cds[rr][c];
            }
            if (curf >= 0) unsafeAtomicAdd(&out[(size_t)curf * 131 + c], sum);
        }
    }
}

// ---------------- round-5 gather edge kernel (ws fallback, unchanged) ----------------
template <int USE_HBF>
__global__ __launch_bounds__(128) void k_edge_s(
    const u16* __restrict__ hbf, const float* __restrict__ nf,
    const int4* __restrict__ sorted, const float* __restrict__ ef,
    const float* __restrict__ We1, const float* __restrict__ be1,
    const float* __restrict__ We2, const float* __restrict__ be2,
    const float* __restrict__ Wc, const float* __restrict__ bc,
    float* __restrict__ out, int NE, int ntiles) {
    __shared__ u16 Xs[32 * 296];
    __shared__ float M2f[32 * 132];
    __shared__ float cds[32][4];
    __shared__ int fidxs[32];
    __shared__ float be1s[128], be2s[128], Wcs[128];
    __shared__ float bcs;

    const int tid = threadIdx.x;
    const int lane = tid & 63;
    const int wv = tid >> 6;
    const int lhi = lane >> 4, llo = lane & 15;
    const f32x4 fzero = {0.f, 0.f, 0.f, 0.f};

    be1s[tid] = be1[tid]; be2s[tid] = be2[tid]; Wcs[tid] = Wc[tid];
    if (tid == 0) bcs = bc[0];

    bf16x8 w1f[4][9];
    bf16x8 w2f[4][4];
#pragma unroll
    for (int ni = 0; ni < 4; ++ni) {
        const int c = wv * 64 + ni * 16 + llo;
#pragma unroll
        for (int t = 0; t < 9; ++t) {
            u16x8 tmp;
#pragma unroll
            for (int j = 0; j < 8; ++j) {
                int k = t * 32 + lhi * 8 + j;
                float v = (k < 273) ? We1[(size_t)k * 128 + c] : 0.f;
                tmp[j] = f2bf(v);
            }
            w1f[ni][t] = __builtin_bit_cast(bf16x8, tmp);
        }
#pragma unroll
        for (int t = 0; t < 4; ++t) {
            u16x8 tmp;
#pragma unroll
            for (int j = 0; j < 8; ++j) {
                int k = t * 32 + lhi * 8 + j;
                tmp[j] = f2bf(We2[(size_t)k * 128 + c]);
            }
            w2f[ni][t] = __builtin_bit_cast(bf16x8, tmp);
        }
    }

    const int cpb = (ntiles + gridDim.x - 1) / gridDim.x;
    const int t0 = blockIdx.x * cpb;
    const int t1 = min(t0 + cpb, ntiles);

    for (int tile = t0; tile < t1; ++tile) {
        const int e0 = tile * 32;
        __syncthreads();
        {
            const int el = tid >> 2, p = tid & 3;
            const int r = e0 + el;
            if (r < NE) {
                const int4 srec = sorted[r];
                const int f = srec.x, s = srec.y, e = srec.z;
                if (USE_HBF) {
                    const uint4* hf = (const uint4*)(hbf + (size_t)f * 128);
                    const uint4* hs = (const uint4*)(hbf + (size_t)s * 128);
                    uint4* df = (uint4*)(Xs + el * 296 + p * 32);
                    df[0] = hf[p * 4 + 0]; df[1] = hf[p * 4 + 1];
                    df[2] = hf[p * 4 + 2]; df[3] = hf[p * 4 + 3];
                    uint4* ds2 = (uint4*)(Xs + el * 296 + 128 + p * 32);
                    ds2[0] = hs[p * 4 + 0]; ds2[1] = hs[p * 4 + 1];
                    ds2[2] = hs[p * 4 + 2]; ds2[3] = hs[p * 4 + 3];
                } else {
                    const float* src = (p < 2) ? (nf + (size_t)f * 131 + 3 + p * 64)
                                               : (nf + (size_t)s * 131 + 3 + (p - 2) * 64);
                    u16* dst = Xs + el * 296 + p * 64;
#pragma unroll
                    for (int q = 0; q < 64; q += 8) {
                        u16x8 v;
#pragma unroll
                        for (int j = 0; j < 8; ++j) v[j] = f2bf(src[q + j]);
                        *(u16x8*)(dst + q) = v;
                    }
                }
                if (p == 0) {
                    const float* ep = ef + (size_t)e * 16;
                    u16* xr = Xs + el * 296;
#pragma unroll
                    for (int j = 0; j < 16; ++j) xr[257 + j] = f2bf(ep[j]);
                } else if (p == 1) {
                    float ax = nf[(size_t)f * 131 + 0], ay = nf[(size_t)f * 131 + 1], az = nf[(size_t)f * 131 + 2];
                    float bx = nf[(size_t)s * 131 + 0], by = nf[(size_t)s * 131 + 1], bz = nf[(size_t)s * 131 + 2];
                    float dx = ax - bx, dy = ay - by, dz = az - bz;
                    cds[el][0] = dx; cds[el][1] = dy; cds[el][2] = dz;
                    Xs[el * 296 + 256] = f2bf(dx * dx + dy * dy + dz * dz);
                    fidxs[el] = f;
                } else if (p == 2) {
                    u16* xr = Xs + el * 296;
#pragma unroll
                    for (int j = 273; j < 288; ++j) xr[j] = 0;
                }
            } else {
                u16* xr = Xs + el * 296;
#pragma unroll
                for (int j = 0; j < 72; ++j) xr[p * 72 + j] = 0;
                if (p == 1) { fidxs[el] = -1; cds[el][0] = cds[el][1] = cds[el][2] = 0.f; }
            }
        }
        __syncthreads();
        f32x4 acc[2][4];
#pragma unroll
        for (int mi = 0; mi < 2; ++mi)
#pragma unroll
            for (int ni = 0; ni < 4; ++ni) acc[mi][ni] = fzero;
        {
            const int arow = llo * 296 + lhi * 8;
            __builtin_amdgcn_s_setprio(1);
#pragma unroll
            for (int t = 0; t < 9; ++t) {
                bf16x8 a0 = ldfrag(Xs + arow + t * 32);
                bf16x8 a1 = ldfrag(Xs + arow + 16 * 296 + t * 32);
#pragma unroll
                for (int ni = 0; ni < 4; ++ni) {
                    acc[0][ni] = MFMA(a0, w1f[ni][t], acc[0][ni]);
                    acc[1][ni] = MFMA(a1, w1f[ni][t], acc[1][ni]);
                }
            }
            __builtin_amdgcn_s_setprio(0);
        }
        __syncthreads();
        u16* ms = Xs;
#pragma unroll
        for (int mi = 0; mi < 2; ++mi) {
#pragma unroll
            for (int ni = 0; ni < 4; ++ni) {
                const int col = wv * 64 + ni * 16 + llo;
                const float b = be1s[col];
#pragma unroll
                for (int r = 0; r < 4; ++r) {
                    const int row = mi * 16 + lhi * 4 + r;
                    ms[row * 136 + col] = f2bf(silu_f(acc[mi][ni][r] + b));
                }
            }
        }
        __syncthreads();
        f32x4 acc2[2][4];
#pragma unroll
        for (int mi = 0; mi < 2; ++mi)
#pragma unroll
            for (int ni = 0; ni < 4; ++ni) acc2[mi][ni] = fzero;
        {
            const int arow = llo * 136 + lhi * 8;
            __builtin_amdgcn_s_setprio(1);
#pragma unroll
            for (int t = 0; t < 4; ++t) {
                bf16x8 a0 = ldfrag(ms + arow + t * 32);
                bf16x8 a1 = ldfrag(ms + arow + 16 * 136 + t * 32);
#pragma unroll
                for (int ni = 0; ni < 4; ++ni) {
                    acc2[0][ni] = MFMA(a0, w2f[ni][t], acc2[0][ni]);
                    acc2[1][ni] = MFMA(a1, w2f[ni][t], acc2[1][ni]);
                }
            }
            __builtin_amdgcn_s_setprio(0);
        }
#pragma unroll
        for (int mi = 0; mi < 2; ++mi) {
#pragma unroll
            for (int ni = 0; ni < 4; ++ni) {
                const int col = wv * 64 + ni * 16 + llo;
                const float b = be2s[col];
#pragma unroll
                for (int r = 0; r < 4; ++r) {
                    const int row = mi * 16 + lhi * 4 + r;
                    M2f[row * 132 + col] = silu_f(acc2[mi][ni][r] + b);
                }
            }
        }
        __syncthreads();
        {
            const int el = tid >> 2, p = tid & 3;
            const float* mrow = M2f + el * 132 + p * 32;
            float dot = 0.f;
#pragma unroll
            for (int i = 0; i < 32; ++i) dot += mrow[i] * Wcs[p * 32 + i];
            dot += __shfl_xor(dot, 1);
            dot += __shfl_xor(dot, 2);
            if (p == 0) {
                const float sc = dot + bcs;
                cds[el][0] *= sc; cds[el][1] *= sc; cds[el][2] *= sc;
            }
        }
        __syncthreads();
        {
            const int col = tid;
            float sum = 0.f;
            int curf = -2;
            for (int k = 0; k < 32; ++k) {
                const int fr = fidxs[k];
                if (fr != curf) {
                    if (curf >= 0) unsafeAtomicAdd(&out[(size_t)curf * 131 + 3 + col], sum);
                    sum = 0.f; curf = fr;
                }
                sum += M2f[k * 132 + col];
            }
            if (curf >= 0) unsafeAtomicAdd(&out[(size_t)curf * 131 + 3 + col], sum);
        }
        if (tid < 48) {
            const int c = tid % 3;
            const int r0 = (tid / 3) * 2;
            float sum = 0.f;
            int curf = -2;
#pragma unroll
            for (int k = 0; k < 2; ++k) {
                const int rr = r0 + k;
                const int fr = fidxs[rr];
                if (fr != curf) {
                    if (curf >= 0) unsafeAtomicAdd(&out[(size_t)curf * 131 + c], sum);
                    sum = 0.f; curf = fr;
                }
                sum += cds[rr][c];
            }
            if (curf >= 0) unsafeAtomicAdd(&out[(size_t)curf * 131 + c], sum);
        }
    }
}

// ---------------- node kernel: 4 waves x 32 cols, high occupancy ----------------
template <int USE_HBF>
__global__ __launch_bounds__(256, 2) void k_node(
    const u16* __restrict__ hbf, const float* __restrict__ nf,
    const int* __restrict__ cnt,
    const float* __restrict__ Wn1, const float* __restrict__ bn1,
    const float* __restrict__ Wn2, const float* __restrict__ bn2,
    float* __restrict__ out, int NN, int ntiles) {
    __shared__ u16 Xs[32 * 264];

    const int tid = threadIdx.x;
    const int lane = tid & 63;
    const int wv = tid >> 6;
    const int lhi = lane >> 4, llo = lane & 15;
    const f32x4 fzero = {0.f, 0.f, 0.f, 0.f};

    bf16x8 w1f[2][8];
    bf16x8 w2f[2][4];
    float b1r[2], b2r[2];
#pragma unroll
    for (int ni = 0; ni < 2; ++ni) {
        const int c = wv * 32 + ni * 16 + llo;
        b1r[ni] = bn1[c]; b2r[ni] = bn2[c];
#pragma unroll
        for (int t = 0; t < 8; ++t) {
            u16x8 tmp;
#pragma unroll
            for (int j = 0; j < 8; ++j) {
                int k = t * 32 + lhi * 8 + j;
                tmp[j] = f2bf(Wn1[(size_t)k * 128 + c]);
            }
            w1f[ni][t] = __builtin_bit_cast(bf16x8, tmp);
        }
#pragma unroll
        for (int t = 0; t < 4; ++t) {
            u16x8 tmp;
#pragma unroll
            for (int j = 0; j < 8; ++j) {
                int k = t * 32 + lhi * 8 + j;
                tmp[j] = f2bf(Wn2[(size_t)k * 128 + c]);
            }
            w2f[ni][t] = __builtin_bit_cast(bf16x8, tmp);
        }
    }

    for (int tile = blockIdx.x; tile < ntiles; tile += gridDim.x) {
        const int n0 = tile * 32;
        __syncthreads();
        {
            const int el = tid >> 3, p = tid & 7;
            const int i = n0 + el;
            if (i < NN) {
                if (p < 4) {
                    u16* dst = Xs + el * 264 + p * 32;
                    if (USE_HBF) {
                        const uint4* hr = (const uint4*)(hbf + (size_t)i * 128 + p * 32);
                        uint4* d = (uint4*)dst;
                        d[0] = hr[0]; d[1] = hr[1]; d[2] = hr[2]; d[3] = hr[3];
                    } else {
                        const float* src = nf + (size_t)i * 131 + 3 + p * 32;
#pragma unroll
                        for (int q = 0; q < 32; q += 8) {
                            u16x8 v;
#pragma unroll
                            for (int j = 0; j < 8; ++j) v[j] = f2bf(src[q + j]);
                            *(u16x8*)(dst + q) = v;
                        }
                    }
                } else {
                    const float* nb = out + (size_t)i * 131 + 3 + (p - 4) * 32;
                    u16* dst = Xs + el * 264 + 128 + (p - 4) * 32;
#pragma unroll
                    for (int q = 0; q < 32; q += 8) {
                        u16x8 v;
#pragma unroll
                        for (int j = 0; j < 8; ++j) v[j] = f2bf(nb[q + j]);
                        *(u16x8*)(dst + q) = v;
                    }
                }
            } else {
                uint4 z = make_uint4(0, 0, 0, 0);
                uint4* d = (uint4*)(Xs + el * 264 + p * 32);
                d[0] = z; d[1] = z; d[2] = z; d[3] = z;
            }
        }
        __syncthreads();
        f32x4 acc[2][2];
#pragma unroll
        for (int mi = 0; mi < 2; ++mi)
#pragma unroll
            for (int ni = 0; ni < 2; ++ni) acc[mi][ni] = fzero;
        {
            const int arow = llo * 264 + lhi * 8;
            __builtin_amdgcn_s_setprio(1);
#pragma unroll
            for (int t = 0; t < 8; ++t) {
                bf16x8 a0 = ldfrag(Xs + arow + t * 32);
                bf16x8 a1 = ldfrag(Xs + arow + 16 * 264 + t * 32);
#pragma unroll
                for (int ni = 0; ni < 2; ++ni) {
                    acc[0][ni] = MFMA(a0, w1f[ni][t], acc[0][ni]);
                    acc[1][ni] = MFMA(a1, w1f[ni][t], acc[1][ni]);
                }
            }
            __builtin_amdgcn_s_setprio(0);
        }
        __syncthreads();
        u16* ms = Xs;
#pragma unroll
        for (int mi = 0; mi < 2; ++mi) {
#pragma unroll
            for (int ni = 0; ni < 2; ++ni) {
                const int col = wv * 32 + ni * 16 + llo;
#pragma unroll
                for (int r = 0; r < 4; ++r) {
                    const int row = mi * 16 + lhi * 4 + r;
                    ms[row * 136 + col] = f2bf(silu_f(acc[mi][ni][r] + b1r[ni]));
                }
            }
        }
        __syncthreads();
        f32x4 acc2[2][2];
#pragma unroll
        for (int mi = 0; mi < 2; ++mi)
#pragma unroll
            for (int ni = 0; ni < 2; ++ni) acc2[mi][ni] = fzero;
        {
            const int arow = llo * 136 + lhi * 8;
            __builtin_amdgcn_s_setprio(1);
#pragma unroll
            for (int t = 0; t < 4; ++t) {
                bf16x8 a0 = ldfrag(ms + arow + t * 32);
                bf16x8 a1 = ldfrag(ms + arow + 16 * 136 + t * 32);
#pragma unroll
                for (int ni = 0; ni < 2; ++ni) {
                    acc2[0][ni] = MFMA(a0, w2f[ni][t], acc2[0][ni]);
                    acc2[1][ni] = MFMA(a1, w2f[ni][t], acc2[1][ni]);
                }
            }
            __builtin_amdgcn_s_setprio(0);
        }
#pragma unroll
        for (int mi = 0; mi < 2; ++mi) {
#pragma unroll
            for (int ni = 0; ni < 2; ++ni) {
                const int col = wv * 32 + ni * 16 + llo;
#pragma unroll
                for (int r = 0; r < 4; ++r) {
                    const int row = mi * 16 + lhi * 4 + r;
                    const int i = n0 + row;
                    if (i < NN) out[(size_t)i * 131 + 3 + col] = acc2[mi][ni][r] + b2r[ni];
                }
            }
        }
        {
            const int el = tid >> 3, c = tid & 7;
            const int i = n0 + el;
            if (c < 3 && i < NN) {
                float cc = out[(size_t)i * 131 + c];
                out[(size_t)i * 131 + c] =
                    nf[(size_t)i * 131 + c] + cc / fmaxf((float)cnt[i], 1.f);
            }
        }
    }
}

extern "C" void kernel_launch(void* const* d_in, const int* in_sizes, int n_in,
                              void* d_out, int out_size, void* d_ws, size_t ws_size,
                              hipStream_t stream) {
    const float* nf = (const float*)d_in[0];
    const int* ei = (const int*)d_in[1];
    const float* ef = (const float*)d_in[2];
    const float* We1 = (const float*)d_in[3];
    const float* be1 = (const float*)d_in[4];
    const float* We2 = (const float*)d_in[5];
    const float* be2 = (const float*)d_in[6];
    const float* Wc = (const float*)d_in[7];
    const float* bc = (const float*)d_in[8];
    const float* Wn1 = (const float*)d_in[9];
    const float* bn1 = (const float*)d_in[10];
    const float* Wn2 = (const float*)d_in[11];
    const float* bn2 = (const float*)d_in[12];

    const int NN = in_sizes[0] / 131;
    const int NE = in_sizes[2] / 16;
    float* out = (float*)d_out;
    char* ws = (char*)d_ws;

    const size_t szN = (size_t)NN * 4;
    const size_t o_cnt = 0;
    const size_t o_cur = szN;
    const size_t o_bsum = 2 * szN;
    const size_t o_sorted = (2 * szN + 4096 + 15) & ~(size_t)15;
    const size_t o_hbf = o_sorted + (size_t)NE * 16;
    const size_t o_cpk = o_hbf + (size_t)NN * 256;
    const size_t o_geo = o_cpk + (size_t)NN * 16;
    const size_t o_yf = o_geo + (size_t)NE * 16;
    const size_t o_ys = o_yf + (size_t)NN * 256;
    const size_t need_core = o_cpk;
    const size_t need_y = o_ys + (size_t)NN * 256;

    hipMemsetAsync(d_out, 0, (size_t)out_size * 4, stream);
    hipMemsetAsync(ws + o_cnt, 0, szN, stream);

    int* cnt = (int*)(ws + o_cnt);
    const int ntiles_n = (NN + 31) / 32;

    if (ws_size >= need_core) {
        int* cursor = (int*)(ws + o_cur);
        int* bsum = (int*)(ws + o_bsum);
        int4* sorted = (int4*)(ws + o_sorted);
        u16* hbf = (u16*)(ws + o_hbf);
        float4* cpk = (float4*)(ws + o_cpk);
        float4* geo = (float4*)(ws + o_geo);
        u16* Yf = (u16*)(ws + o_yf);
        u16* Ys = (u16*)(ws + o_ys);
        const bool use_y = ws_size >= need_y;

        k_prep<<<(NN * 16 + 255) / 256, 256, 0, stream>>>(nf, hbf, use_y ? cpk : nullptr, NN);
        k_hist<<<(NE + 255) / 256, 256, 0, stream>>>(ei, cnt, NE);
        const int NB = (NN + 1023) / 1024;
        k_scanA<<<NB, 256, 0, stream>>>(cnt, cursor, bsum, NN);
        k_scanB<<<1, 64, 0, stream>>>(bsum, NB);
        k_scanC<<<(NN + 255) / 256, 256, 0, stream>>>(cursor, bsum, NN);
        k_scatter<<<(NE + 255) / 256, 256, 0, stream>>>(ei, ei + NE, cursor, sorted,
                                                        cpk, use_y ? geo : nullptr, NE);

        if (use_y) {
            k_ymm<<<ntiles_n, 256, 0, stream>>>(hbf, We1, be1, Yf, Ys, NN, ntiles_n);
            const int ntiles_e = (NE + 31) / 32;
            k_edge_y<<<2048, 128, 0, stream>>>(Yf, Ys, sorted, geo, ef, We1,
                                               We2, be2, Wc, bc, out, NE, ntiles_e);
        } else {
            const int ntiles_e = (NE + 31) / 32;
            k_edge_s<1><<<1024, 128, 0, stream>>>(hbf, nf, sorted, ef,
                                                  We1, be1, We2, be2, Wc, bc, out, NE, ntiles_e);
        }
        k_node<1><<<ntiles_n, 256, 0, stream>>>(hbf, nf, cnt, Wn1, bn1, Wn2, bn2, out, NN, ntiles_n);
    } else {
        int* cursor = (int*)(ws + o_cur);
        int* bsum = (int*)(ws + o_bsum);
        int4* sorted = (int4*)(ws + o_sorted);
        const bool have_sort = ws_size >= o_hbf;
        k_hist<<<(NE + 255) / 256, 256, 0, stream>>>(ei, cnt, NE);
        if (have_sort) {
            const int NB = (NN + 1023) / 1024;
            k_scanA<<<NB, 256, 0, stream>>>(cnt, cursor, bsum, NN);
            k_scanB<<<1, 64, 0, stream>>>(bsum, NB);
            k_scanC<<<(NN + 255) / 256, 256, 0, stream>>>(cursor, bsum, NN);
            k_scatter<<<(NE + 255) / 256, 256, 0, stream>>>(ei, ei + NE, cursor, sorted,
                                                            nullptr, nullptr, NE);
            const int ntiles_e = (NE + 31) / 32;
            k_edge_s<0><<<1024, 128, 0, stream>>>(nullptr, nf, sorted, ef,
                                                  We1, be1, We2, be2, Wc, bc, out, NE, ntiles_e);
        }
        k_node<0><<<ntiles_n, 256, 0, stream>>>(nullptr, nf, cnt, Wn1, bn1, Wn2, bn2, out, NN, ntiles_n);
    }
}